// Round 18
// baseline (805.330 us; speedup 1.0000x reference)
//
#include <hip/hip_runtime.h>

// Problem constants (from reference setup_inputs).
constexpr int B = 8;
constexpr int N = 16384;
constexpr int M = 1024;
constexpr int C = 256;

typedef float vf16 __attribute__((ext_vector_type(16)));

// d_ws layout: int cnt[8] | unsigned short vlist[8][16384]  (~256KB + 64B).

__global__ void clear_cnt_kernel(int* cnt) {
    if (threadIdx.x < 8) cnt[threadIdx.x] = 0;
}

// Append valid row ids per batch. Order nondeterministic; output independent
// of order (each point computed independently, bit-exact) -> deterministic.
__global__ __launch_bounds__(256) void compact_kernel(
    const int* __restrict__ masks, int* __restrict__ cnt,
    unsigned short* __restrict__ vlist)
{
    const int g = blockIdx.x * 256 + threadIdx.x;  // 0..B*N-1
    const int b = g >> 14, n = g & 16383;
    if (masks[g] != 0) {
        const int pos = atomicAdd(&cnt[b], 1);     // device-scope; wave-coalesced
        vlist[b * 16384 + pos] = (unsigned short)n;
    }
}

// Main: grid 8 x 512 (b = blk&7 XCD swizzle; idx = blk>>3).
//   idx <  256: VALID role — r10's proven scan (SMEM s_load candidate stream,
//               bit-exact ladder, u64-key merge) on 64 compacted points.
//   idx >= 256: ZERO role — pure stores: zero-fill invalid rows (mask==0).
// Zero-role blocks are pure-VMEM and co-schedule with VALU-heavy scan blocks
// on the same CUs -> compute/store overlap. Every output row written once.
__global__ __launch_bounds__(256, 8) void upsample_idw_kernel(
    const float* __restrict__ xyz,          // [B,N,3]
    const float* __restrict__ sxyz,         // [B,M,3]
    const float* __restrict__ feats,        // [B,M,C]
    const int*   __restrict__ masks,        // [B,N]
    const int*   __restrict__ cnt,          // [8] valid counts
    const unsigned short* __restrict__ vlist, // [8][16384] valid row ids
    float*       __restrict__ out)          // [B,N,C]
{
    const int tid = threadIdx.x;
    const int w   = tid >> 6;               // wave id
    const int l   = tid & 63;               // lane
    const int blk = blockIdx.x;
    const int b   = blk & 7;                // batch == XCD (round-robin dispatch)
    const int idx = blk >> 3;               // 0..511

    if (idx >= 256) {
        // ================= ZERO role: fill invalid rows =================
        const int nb = (idx - 256) * 64;    // first row of this chunk
        const int mv = masks[(size_t)b * N + nb + l];   // 64 rows, all waves same
        const unsigned long long bits = __ballot(mv == 0);
        const float4 z4 = make_float4(0.f, 0.f, 0.f, 0.f);
        for (int p = w * 16; p < w * 16 + 16; ++p) {    // wave w owns 16 rows
            if ((bits >> p) & 1ULL) {       // wave-uniform branch
                float4* orow = (float4*)(out + ((size_t)b * N + nb + p) * C);
                orow[l] = z4;               // 64 lanes x 16B = 1KB coalesced
            }
        }
        return;
    }

    // ================= VALID role: scan 64 compacted points =================
    const int cnt_b = cnt[b];
    const int base  = idx * 64;
    if (base >= cnt_b) return;              // uniform early exit

    __shared__ unsigned long long s_key[64][4][3];   // 6KB
    __shared__ float s_w[64][3];
    __shared__ int   s_j[64][4];            // j0, j1, j2 (unused slot)
    __shared__ int   s_row[64];             // global row per local point (-1 pad)

    const int i   = base + l;
    const int row = (i < cnt_b) ? (int)vlist[b * 16384 + i] : -1;
    const int crow = (row >= 0) ? row : 0;  // dummy lanes scan row 0 (discarded)

    // Own point coords (replicated across the 4 waves).
    const float* xp = xyz + ((size_t)b * N + crow) * 3;
    const float x = xp[0], y = xp[1], z = xp[2];
    if (tid < 64) s_row[tid] = row;

    // BLOCK-uniform batch base (SGPR pair for s_load); wave-quarter byte
    // offset forced uniform via readfirstlane into the SMEM soffset operand.
    const float* bbase = sxyz + (size_t)b * (M * 3);
    const int qoff = __builtin_amdgcn_readfirstlane((tid >> 6) * (256 * 12));

    float d0 = __builtin_inff(), d1 = __builtin_inff(), d2 = __builtin_inff();
    int   i0 = 0, i1 = 0, i2 = 0;

    for (int ch = 0; ch < 16; ++ch) {       // 16 chunks x 16 candidates
        vf16 ca, cb, cc;                    // 48 floats = 16 candidates in SGPRs
        const int off = qoff + ch * 192;    // uniform byte offset
        asm volatile(
            "s_load_dwordx16 %0, %3, %4\n\t"
            "s_load_dwordx16 %1, %3, %4 offset:64\n\t"
            "s_load_dwordx16 %2, %3, %4 offset:128\n\t"
            "s_waitcnt lgkmcnt(0)"
            : "=&s"(ca), "=&s"(cb), "=&s"(cc)
            : "s"(bbase), "s"(off));
        #pragma unroll
        for (int j = 0; j < 16; ++j) {
            const int f0 = 3 * j, f1 = 3 * j + 1, f2 = 3 * j + 2;
            const float cx = (f0 < 16) ? ca[f0 & 15] : (f0 < 32) ? cb[f0 & 15] : cc[f0 & 15];
            const float cy = (f1 < 16) ? ca[f1 & 15] : (f1 < 32) ? cb[f1 & 15] : cc[f1 & 15];
            const float cz = (f2 < 16) ? ca[f2 & 15] : (f2 < 32) ? cb[f2 & 15] : cc[f2 & 15];
            // (c - x): negated dx, identical after squaring (IEEE exact).
            const float dx = __fsub_rn(cx, x);
            const float dy = __fsub_rn(cy, y);
            const float dz = __fsub_rn(cz, z);
            const float d  = __fadd_rn(__fadd_rn(__fmul_rn(dx, dx), __fmul_rn(dy, dy)),
                                       __fmul_rn(dz, dz));
            const int m = ch * 16 + j;      // uniform value
            // Strict < keeps earlier (lower) index on ties (matches top_k).
            const bool lt0 = d < d0, lt1 = d < d1, lt2 = d < d2;
            i2 = lt1 ? i1 : (lt2 ? m : i2);
            i1 = lt0 ? i0 : (lt1 ? m : i1);
            i0 = lt0 ? m  : i0;
            // Exact value ladder: min + 2x med3 (selection only, no rounding).
            const float nd2 = __builtin_amdgcn_fmed3f(d1, d2, d);
            const float nd1 = __builtin_amdgcn_fmed3f(d0, d1, d);
            d2 = nd2; d1 = nd1; d0 = fminf(d0, d);
        }
    }

    // Pack (dist_bits, global_idx): monotone u64, lowest-index tie-break.
    const unsigned kbase = (unsigned)(w * 256);
    s_key[l][w][0] = ((unsigned long long)__float_as_uint(d0) << 32) | (kbase + (unsigned)i0);
    s_key[l][w][1] = ((unsigned long long)__float_as_uint(d1) << 32) | (kbase + (unsigned)i1);
    s_key[l][w][2] = ((unsigned long long)__float_as_uint(d2) << 32) | (kbase + (unsigned)i2);
    __syncthreads();

    // ---- Merge: 12 candidates -> top-3 (one thread per point) ----
    if (tid < 64) {
        unsigned long long k0 = ~0ULL, k1 = ~0ULL, k2 = ~0ULL;
        #pragma unroll
        for (int q = 0; q < 4; ++q) {
            #pragma unroll
            for (int s = 0; s < 3; ++s) {
                const unsigned long long k = s_key[tid][q][s];
                const bool lt0 = k < k0, lt1 = k < k1, lt2 = k < k2;
                k2 = lt1 ? k1 : (lt2 ? k : k2);
                k1 = lt0 ? k0 : (lt1 ? k : k1);
                k0 = lt0 ? k  : k0;
            }
        }
        const float e0 = __uint_as_float((unsigned)(k0 >> 32));
        const float e1 = __uint_as_float((unsigned)(k1 >> 32));
        const float e2 = __uint_as_float((unsigned)(k2 >> 32));
        const float m0 = fmaxf(e0, 1e-10f);
        const float m1 = fmaxf(e1, 1e-10f);
        const float m2 = fmaxf(e2, 1e-10f);
        float w0 = 1.0f / (m0 * m0 + 1e-10f);
        float w1 = 1.0f / (m1 * m1 + 1e-10f);
        float w2 = 1.0f / (m2 * m2 + 1e-10f);
        const float scale = 1.0f / (w0 + w1 + w2);   // all listed points valid
        s_w[tid][0] = w0 * scale;
        s_w[tid][1] = w1 * scale;
        s_w[tid][2] = w2 * scale;
        s_j[tid][0] = (int)(unsigned)k0;
        s_j[tid][1] = (int)(unsigned)k1;
        s_j[tid][2] = (int)(unsigned)k2;
    }
    __syncthreads();

    // ---- Phase 2: 4 points x 64 channel-quads per iteration ----
    const int pq = tid >> 6;                 // sub-point (= wave id)
    const int cq = tid & 63;                 // channel quad
    const float4* Fb4 = (const float4*)(feats + (size_t)b * (M * C));
    float4* ob4 = (float4*)(out + ((size_t)b * N) * C);

    for (int p0 = 0; p0 < 64; p0 += 4) {
        const int p = p0 + pq;               // wave-uniform
        const int prow = __builtin_amdgcn_readfirstlane(s_row[p]);
        if (prow >= 0) {                     // scalar branch (skip pad lanes)
            const int j0 = __builtin_amdgcn_readfirstlane(s_j[p][0]);
            const int j1 = __builtin_amdgcn_readfirstlane(s_j[p][1]);
            const int j2 = __builtin_amdgcn_readfirstlane(s_j[p][2]);
            const float w0 = __uint_as_float(
                __builtin_amdgcn_readfirstlane((int)__float_as_uint(s_w[p][0])));
            const float w1 = __uint_as_float(
                __builtin_amdgcn_readfirstlane((int)__float_as_uint(s_w[p][1])));
            const float w2 = __uint_as_float(
                __builtin_amdgcn_readfirstlane((int)__float_as_uint(s_w[p][2])));
            const float4 f0 = Fb4[j0 * 64 + cq];
            const float4 f1 = Fb4[j1 * 64 + cq];
            const float4 f2 = Fb4[j2 * 64 + cq];
            float4 acc;
            acc.x = fmaf(w2, f2.x, fmaf(w1, f1.x, w0 * f0.x));
            acc.y = fmaf(w2, f2.y, fmaf(w1, f1.y, w0 * f0.y));
            acc.z = fmaf(w2, f2.z, fmaf(w1, f1.z, w0 * f0.z));
            acc.w = fmaf(w2, f2.w, fmaf(w1, f1.w, w0 * f0.w));
            ob4[(size_t)prow * 64 + cq] = acc;
        }
    }
}

extern "C" void kernel_launch(void* const* d_in, const int* in_sizes, int n_in,
                              void* d_out, int out_size, void* d_ws, size_t ws_size,
                              hipStream_t stream) {
    const float* xyz   = (const float*)d_in[0];
    const float* sxyz  = (const float*)d_in[1];
    const float* feats = (const float*)d_in[2];
    const int*   masks = (const int*)d_in[3];
    float*       out   = (float*)d_out;

    int* cnt = (int*)d_ws;                              // 8 ints
    unsigned short* vlist = (unsigned short*)((char*)d_ws + 64);  // 256KB

    hipLaunchKernelGGL(clear_cnt_kernel, dim3(1), dim3(8), 0, stream, cnt);
    hipLaunchKernelGGL(compact_kernel, dim3(B * N / 256), dim3(256), 0, stream,
                       masks, cnt, vlist);
    hipLaunchKernelGGL(upsample_idw_kernel, dim3(B * 512), dim3(256), 0, stream,
                       xyz, sxyz, feats, masks, cnt, vlist, out);
}